// Round 3
// baseline (843.551 us; speedup 1.0000x reference)
//
#include <hip/hip_runtime.h>
#include <hip/hip_bf16.h>

#define BB 64
#define SS 2048
#define DD 512
#define UU 512
#define BS (BB*SS)   // 131072

typedef __attribute__((ext_vector_type(8))) short bf16x8;
typedef __attribute__((ext_vector_type(16))) float f32x16;

static __device__ __forceinline__ unsigned short f2bf(float x) {
    union { float f; unsigned int u; } v; v.f = x;
    unsigned int r = v.u + 0x7FFFu + ((v.u >> 16) & 1u);
    return (unsigned short)(r >> 16);
}

// ---- prep: blocks 0..63 pack W2 -> W2F (MFMA B-fragment-major, bf16);
//            blocks 64..191 qproj (128 blocks: b x u-half, ILP-pipelined) ----
__global__ void k_prep(const float* __restrict__ W2, unsigned short* __restrict__ W2F,
                       const float* __restrict__ query, const float* __restrict__ W1,
                       const float* __restrict__ b1, const float* __restrict__ b2,
                       float* __restrict__ qpb) {
    __shared__ float tile[64][65];
    __shared__ float qs[512];
    const int t = threadIdx.x;
    if (blockIdx.x < 64) {
        const int ti = blockIdx.x >> 3;   // d-tile (k)
        const int tj = blockIdx.x & 7;    // u-tile (n)
        #pragma unroll
        for (int i = 0; i < 16; ++i) {
            int e = i*256 + t;
            int dr = e >> 6, uc = e & 63;
            tile[dr][uc] = W2[(size_t)(ti*64+dr)*UU + tj*64+uc];
        }
        __syncthreads();
        const int ksl = t >> 6, ln = t & 63;
        const int lh = ln >> 5, l31 = ln & 31;
        #pragma unroll
        for (int ntl = 0; ntl < 2; ++ntl) {
            const int ks = ti*4 + ksl;
            const int ntile = tj*2 + ntl;
            bf16x8 g;
            #pragma unroll
            for (int j = 0; j < 8; ++j)
                g[j] = (short)f2bf(tile[ksl*16 + lh*8 + j][ntl*32 + l31]);
            *(bf16x8*)&W2F[(size_t)(((ks*16 + ntile)*64 + ln) * 8)] = g;
        }
    } else {
        const int idx = blockIdx.x - 64;
        const int b  = idx >> 1;          // batch
        const int uh = idx & 1;           // u-half
        const int u  = uh*256 + t;
        if (t < 256) { qs[t] = query[b*DD + t]; qs[t+256] = query[b*DD + t + 256]; }
        __syncthreads();
        float p0 = 0.f, p1 = 0.f, p2 = 0.f, p3 = 0.f;
        #pragma unroll 2
        for (int d = 0; d < DD; d += 4) {
            p0 = fmaf(qs[d+0], W1[(size_t)(d+0)*UU + u], p0);
            p1 = fmaf(qs[d+1], W1[(size_t)(d+1)*UU + u], p1);
            p2 = fmaf(qs[d+2], W1[(size_t)(d+2)*UU + u], p2);
            p3 = fmaf(qs[d+3], W1[(size_t)(d+3)*UU + u], p3);
        }
        qpb[b*UU + u] = (p0 + p1) + (p2 + p3) + b1[u] + b2[u];
    }
}

// ---- persistent pipelined scores: 256 blocks x 8 tiles, double-buffered A ----
// Per tile: K-loop (32 ksteps, B-ring depth 4) interleaved with staging of the
// NEXT tile (issue-early loads, convert+ds_write spread across kstep groups).
// Raw s_barrier + lgkmcnt(0) only -> vmcnt never drained (loads live across barriers).
__launch_bounds__(512, 2)
__global__ void k_scores(const float* __restrict__ values,
                         const unsigned short* __restrict__ W2F,
                         const float* __restrict__ qpb,
                         const float* __restrict__ Vw,
                         float* __restrict__ pm, float* __restrict__ pl,
                         float* __restrict__ pv) {
    __shared__ unsigned short Albuf[2][64*512];   // 2 x 64 KB A double-buffer
    __shared__ float sred[512];                   // [8 waves][64 rows]
    const int t    = threadIdx.x;
    const int blk  = blockIdx.x;
    const int wave = t >> 6, lane = t & 63;
    const int ln31 = lane & 31, half = lane >> 5;
    const int b    = blk >> 2;                    // batch constant per block
    const int srow = t >> 6;                      // staging sub-row within chunk
    const int sg   = t & 63;                      // staging granule

    // --- B-ring prologue: depth-4, persists across tiles ((ks+4)&31 wrap) ---
    const bf16x8* Bp = (const bf16x8*)W2F;
    bf16x8 bfr[4][2];
    #pragma unroll
    for (int s = 0; s < 4; ++s)
        #pragma unroll
        for (int nt = 0; nt < 2; ++nt)
            bfr[s][nt] = Bp[(s*16 + wave*2 + nt)*64 + lane];

    // epilogue constants
    float qv[2], vw[2];
    #pragma unroll
    for (int nt = 0; nt < 2; ++nt) {
        int n = wave*64 + nt*32 + ln31;
        qv[nt] = qpb[b*UU + n];
        vw[nt] = Vw[n];
    }

    // --- prologue: stage tile 0 into buf0 (swizzle key = row&31) ---
    {
        const float* src0 = values + (size_t)blk * 8 * 64 * DD;
        #pragma unroll
        for (int c = 0; c < 8; ++c) {
            const int row = c*8 + srow;
            const float4 f0 = *(const float4*)(src0 + (size_t)row*DD + sg*8);
            const float4 f1 = *(const float4*)(src0 + (size_t)row*DD + sg*8 + 4);
            bf16x8 pk;
            pk[0] = (short)f2bf(f0.x); pk[1] = (short)f2bf(f0.y);
            pk[2] = (short)f2bf(f0.z); pk[3] = (short)f2bf(f0.w);
            pk[4] = (short)f2bf(f1.x); pk[5] = (short)f2bf(f1.y);
            pk[6] = (short)f2bf(f1.z); pk[7] = (short)f2bf(f1.w);
            *(bf16x8*)&Albuf[0][row*512 + ((sg ^ (row & 31)) << 3)] = pk;
        }
    }
    asm volatile("s_waitcnt lgkmcnt(0)" ::: "memory");
    __builtin_amdgcn_s_barrier();

    int cur = 0;
    for (int i = 0; i < 8; ++i) {
        const int tile = blk*8 + i;
        const size_t m0 = (size_t)tile * 64;
        const unsigned short* Ab = Albuf[cur];
        unsigned short* An = Albuf[cur ^ 1];
        const float* nsrc = values + (m0 + 64) * DD;
        const bool st = (i < 7);

        float4 sreg[16];
        auto issue2 = [&](int c) {
            const int row = c*8 + srow;
            sreg[2*c]   = *(const float4*)(nsrc + (size_t)row*DD + sg*8);
            sreg[2*c+1] = *(const float4*)(nsrc + (size_t)row*DD + sg*8 + 4);
        };
        auto flush2 = [&](int c) {
            const int row = c*8 + srow;
            bf16x8 pk;
            pk[0] = (short)f2bf(sreg[2*c].x);   pk[1] = (short)f2bf(sreg[2*c].y);
            pk[2] = (short)f2bf(sreg[2*c].z);   pk[3] = (short)f2bf(sreg[2*c].w);
            pk[4] = (short)f2bf(sreg[2*c+1].x); pk[5] = (short)f2bf(sreg[2*c+1].y);
            pk[6] = (short)f2bf(sreg[2*c+1].z); pk[7] = (short)f2bf(sreg[2*c+1].w);
            *(bf16x8*)&An[row*512 + ((sg ^ (row & 31)) << 3)] = pk;
        };

        if (st) { issue2(0); issue2(1); issue2(2); issue2(3); }

        f32x16 acc[2][2];
        #pragma unroll
        for (int mt = 0; mt < 2; ++mt)
            #pragma unroll
            for (int nt = 0; nt < 2; ++nt)
                #pragma unroll
                for (int r = 0; r < 16; ++r)
                    acc[mt][nt][r] = 0.f;

        // --- K-loop: 4 groups x 8 ksteps; stage actions between groups ---
        #pragma unroll
        for (int grp = 0; grp < 4; ++grp) {
            #pragma unroll
            for (int k8 = 0; k8 < 8; ++k8) {
                const int ks = grp*8 + k8;
                const int slot = ks & 3;
                const int g8 = (((ks*2 + half) ^ ln31) << 3);
                bf16x8 a0 = *(const bf16x8*)&Ab[ln31*512 + g8];
                bf16x8 a1 = *(const bf16x8*)&Ab[16384 + ln31*512 + g8];
                acc[0][0] = __builtin_amdgcn_mfma_f32_32x32x16_bf16(a0, bfr[slot][0], acc[0][0], 0, 0, 0);
                acc[1][0] = __builtin_amdgcn_mfma_f32_32x32x16_bf16(a1, bfr[slot][0], acc[1][0], 0, 0, 0);
                acc[0][1] = __builtin_amdgcn_mfma_f32_32x32x16_bf16(a0, bfr[slot][1], acc[0][1], 0, 0, 0);
                acc[1][1] = __builtin_amdgcn_mfma_f32_32x32x16_bf16(a1, bfr[slot][1], acc[1][1], 0, 0, 0);
                const int nk = (ks + 4) & 31;   // wraps to next tile's prologue state
                bfr[slot][0] = Bp[(nk*16 + wave*2 + 0)*64 + lane];
                bfr[slot][1] = Bp[(nk*16 + wave*2 + 1)*64 + lane];
            }
            if (st) {
                if (grp == 0)      { flush2(0); flush2(1); issue2(4); issue2(5); }
                else if (grp == 1) { flush2(2); flush2(3); issue2(6); issue2(7); }
                else if (grp == 2) { flush2(4); flush2(5); }
                else               { flush2(6); flush2(7); }
            }
        }

        // B1: A-buffer handoff (lgkm only; vmcnt stays in flight)
        asm volatile("s_waitcnt lgkmcnt(0)" ::: "memory");
        __builtin_amdgcn_s_barrier();

        // --- epilogue: tanh + V-dot partials -> sred ---
        #pragma unroll
        for (int mt = 0; mt < 2; ++mt) {
            float s[16];
            #pragma unroll
            for (int r = 0; r < 16; ++r) s[r] = 0.f;
            #pragma unroll
            for (int nt = 0; nt < 2; ++nt) {
                const float q = qv[nt], w = vw[nt];
                #pragma unroll
                for (int r = 0; r < 16; ++r) {
                    float x = q + acc[mt][nt][r];
                    float e = __expf(x + x);
                    float rc = __builtin_amdgcn_rcpf(e + 1.f);
                    s[r] = fmaf(fmaf(-2.f, rc, 1.f), w, s[r]);
                }
            }
            #pragma unroll
            for (int r = 0; r < 16; ++r) {
                float v = s[r];
                v += __shfl_xor(v, 1);
                v += __shfl_xor(v, 2);
                v += __shfl_xor(v, 4);
                v += __shfl_xor(v, 8);
                v += __shfl_xor(v, 16);
                if (ln31 == 0)
                    sred[wave*64 + mt*32 + (r & 3) + 8*(r >> 2) + 4*half] = v;
            }
        }
        asm volatile("s_waitcnt lgkmcnt(0)" ::: "memory");
        __builtin_amdgcn_s_barrier();

        // --- redundant per-wave softmax: row = lane, p stays in registers ---
        float ssum = 0.f;
        #pragma unroll
        for (int w = 0; w < 8; ++w) ssum += sred[w*64 + lane];
        float mx = ssum;
        #pragma unroll
        for (int off = 32; off; off >>= 1) mx = fmaxf(mx, __shfl_xor(mx, off));
        float p = __expf(ssum - mx);
        float l = p;
        #pragma unroll
        for (int off = 32; off; off >>= 1) l += __shfl_xor(l, off);
        if (t == 0) { pm[tile] = mx; pl[tile] = l; }

        // --- context: each thread one d-column, p broadcast via shfl ---
        float ca = 0.f;
        const float* vcol = values + m0*DD + t;
        #pragma unroll 8
        for (int r = 0; r < 64; ++r) {
            float pr = __shfl(p, r);
            ca = fmaf(pr, vcol[(size_t)r*DD], ca);
        }
        pv[(size_t)tile*DD + t] = ca;

        cur ^= 1;
    }
}

// ---- finish: combine 32 chunks per batch with online-softmax rescale ----
__global__ void k_finish(const float* __restrict__ pv, const float* __restrict__ pm,
                         const float* __restrict__ pl, float* __restrict__ out) {
    __shared__ float sm_[32], sl_[32], sw[32];
    const int b = blockIdx.x, t = threadIdx.x;
    if (t < 32) { sm_[t] = pm[b*32 + t]; sl_[t] = pl[b*32 + t]; }
    __syncthreads();
    float M = -1e30f;
    #pragma unroll
    for (int c = 0; c < 32; ++c) M = fmaxf(M, sm_[c]);
    float L = 0.f;
    #pragma unroll
    for (int c = 0; c < 32; ++c) L += sl_[c] * __expf(sm_[c] - M);
    if (t < 32) sw[t] = __expf(sm_[t] - M) / L;
    __syncthreads();
    float2 a = make_float2(0.f, 0.f);
    #pragma unroll 4
    for (int c = 0; c < 32; ++c) {
        float w = sw[c];
        float2 v = *(const float2*)&pv[(size_t)(b*32 + c)*DD + t*2];
        a.x = fmaf(w, v.x, a.x);
        a.y = fmaf(w, v.y, a.y);
    }
    *(float2*)&out[(size_t)b*DD + t*2] = a;
}

extern "C" void kernel_launch(void* const* d_in, const int* in_sizes, int n_in,
                              void* d_out, int out_size, void* d_ws, size_t ws_size,
                              hipStream_t stream) {
    const float* query  = (const float*)d_in[0];
    const float* values = (const float*)d_in[1];
    const float* W1     = (const float*)d_in[2];
    const float* b1     = (const float*)d_in[3];
    const float* W2     = (const float*)d_in[4];
    const float* b2     = (const float*)d_in[5];
    const float* Vw     = (const float*)d_in[6];
    // d_in[7] = bv: softmax over s is shift-invariant -> no-op

    char* ws = (char*)d_ws;
    unsigned short* W2F = (unsigned short*)ws;            // 512 KB + 32 KB pad
    float* qpb = (float*)(ws + 557056);                   // 128 KB
    float* pm  = (float*)(ws + 557056 + 131072);          // 8 KB
    float* pl  = (float*)(ws + 557056 + 131072 + 8192);   // 8 KB
    float* pv  = (float*)(ws + 557056 + 131072 + 16384);  // 4 MB

    k_prep<<<192, 256, 0, stream>>>(W2, W2F, query, W1, b1, b2, qpb);
    k_scores<<<256, 512, 0, stream>>>(values, W2F, qpb, Vw, pm, pl, pv);
    k_finish<<<BB, 256, 0, stream>>>(pv, pm, pl, (float*)d_out);
}

// Round 4
// 475.284 us; speedup vs baseline: 1.7748x; 1.7748x over previous
//
#include <hip/hip_runtime.h>
#include <hip/hip_bf16.h>

#define BB 64
#define SS 2048
#define DD 512
#define UU 512
#define BS (BB*SS)   // 131072

typedef __attribute__((ext_vector_type(8))) short bf16x8;
typedef __attribute__((ext_vector_type(16))) float f32x16;

static __device__ __forceinline__ unsigned short f2bf(float x) {
    union { float f; unsigned int u; } v; v.f = x;
    unsigned int r = v.u + 0x7FFFu + ((v.u >> 16) & 1u);
    return (unsigned short)(r >> 16);
}

// ---- prep: blocks 0..63 pack W2 -> W2F (MFMA B-fragment-major, bf16);
//            blocks 64..191 qproj (128 blocks: b x u-half, ILP-pipelined) ----
__global__ void k_prep(const float* __restrict__ W2, unsigned short* __restrict__ W2F,
                       const float* __restrict__ query, const float* __restrict__ W1,
                       const float* __restrict__ b1, const float* __restrict__ b2,
                       float* __restrict__ qpb) {
    __shared__ float tile[64][65];
    __shared__ float qs[512];
    const int t = threadIdx.x;
    if (blockIdx.x < 64) {
        const int ti = blockIdx.x >> 3;   // d-tile (k)
        const int tj = blockIdx.x & 7;    // u-tile (n)
        #pragma unroll
        for (int i = 0; i < 16; ++i) {
            int e = i*256 + t;
            int dr = e >> 6, uc = e & 63;
            tile[dr][uc] = W2[(size_t)(ti*64+dr)*UU + tj*64+uc];
        }
        __syncthreads();
        const int ksl = t >> 6, ln = t & 63;
        const int lh = ln >> 5, l31 = ln & 31;
        #pragma unroll
        for (int ntl = 0; ntl < 2; ++ntl) {
            const int ks = ti*4 + ksl;
            const int ntile = tj*2 + ntl;
            bf16x8 g;
            #pragma unroll
            for (int j = 0; j < 8; ++j)
                g[j] = (short)f2bf(tile[ksl*16 + lh*8 + j][ntl*32 + l31]);
            *(bf16x8*)&W2F[(size_t)(((ks*16 + ntile)*64 + ln) * 8)] = g;
        }
    } else {
        const int idx = blockIdx.x - 64;
        const int b  = idx >> 1;          // batch
        const int uh = idx & 1;           // u-half
        const int u  = uh*256 + t;
        if (t < 256) { qs[t] = query[b*DD + t]; qs[t+256] = query[b*DD + t + 256]; }
        __syncthreads();
        float p0 = 0.f, p1 = 0.f, p2 = 0.f, p3 = 0.f;
        #pragma unroll 2
        for (int d = 0; d < DD; d += 4) {
            p0 = fmaf(qs[d+0], W1[(size_t)(d+0)*UU + u], p0);
            p1 = fmaf(qs[d+1], W1[(size_t)(d+1)*UU + u], p1);
            p2 = fmaf(qs[d+2], W1[(size_t)(d+2)*UU + u], p2);
            p3 = fmaf(qs[d+3], W1[(size_t)(d+3)*UU + u], p3);
        }
        qpb[b*UU + u] = (p0 + p1) + (p2 + p3) + b1[u] + b2[u];
    }
}

// ---- fused scores + softmax stats + fp32 partial context ----
// 64 rows/block, 2048 blocks (2/CU), N=512 (8 waves x 64 cols), K=512.
// Grafts vs the 195us baseline: row&31 zero-conflict swizzle, depth-4 B-ring,
// raw s_barrier + lgkm-only waits (B vmcnt never drained), redundant per-wave
// softmax (no wave0 serial phase), setprio around MFMA quad.
__launch_bounds__(512, 4)
__global__ void k_scores(const float* __restrict__ values,
                         const unsigned short* __restrict__ W2F,
                         const float* __restrict__ qpb,
                         const float* __restrict__ Vw,
                         float* __restrict__ pm, float* __restrict__ pl,
                         float* __restrict__ pv) {
    __shared__ unsigned short Albuf[64*512];   // 64 KB: A rows resident, full K
    const int t   = threadIdx.x;
    const int blk = blockIdx.x;
    const int m0  = blk * 64;
    const int b   = blk >> 5;                  // 32 blocks per batch
    const int wave = t >> 6, lane = t & 63;
    const int ln31 = lane & 31, half = lane >> 5;

    // --- B prologue: depth-4 ring, frag-contiguous coalesced loads ---
    const bf16x8* Bp = (const bf16x8*)W2F;
    bf16x8 bfr[4][2];
    #pragma unroll
    for (int s = 0; s < 4; ++s)
        #pragma unroll
        for (int nt = 0; nt < 2; ++nt)
            bfr[s][nt] = Bp[(s*16 + wave*2 + nt)*64 + lane];

    // epilogue constants
    float qv[2], vw[2];
    #pragma unroll
    for (int nt = 0; nt < 2; ++nt) {
        int n = wave*64 + nt*32 + ln31;
        qv[nt] = qpb[b*UU + n];
        vw[nt] = Vw[n];
    }

    // --- stage A: fp32 -> bf16, zero-conflict XOR swizzle (key row&31) ---
    const float* src = values + (size_t)m0 * DD;
    #pragma unroll
    for (int i = 0; i < 8; ++i) {
        int gf  = i*512 + t;
        int row = gf >> 6;
        int g   = gf & 63;
        const float4 f0 = *(const float4*)(src + (size_t)row*DD + g*8);
        const float4 f1 = *(const float4*)(src + (size_t)row*DD + g*8 + 4);
        bf16x8 pk;
        pk[0] = (short)f2bf(f0.x); pk[1] = (short)f2bf(f0.y);
        pk[2] = (short)f2bf(f0.z); pk[3] = (short)f2bf(f0.w);
        pk[4] = (short)f2bf(f1.x); pk[5] = (short)f2bf(f1.y);
        pk[6] = (short)f2bf(f1.z); pk[7] = (short)f2bf(f1.w);
        *(bf16x8*)&Albuf[row*512 + ((g ^ (row & 31)) << 3)] = pk;
    }
    asm volatile("s_waitcnt lgkmcnt(0)" ::: "memory");
    __builtin_amdgcn_s_barrier();

    // --- K-loop: 32 ksteps, 4 MFMA each per wave, no barriers ---
    f32x16 acc[2][2];
    #pragma unroll
    for (int mt = 0; mt < 2; ++mt)
        #pragma unroll
        for (int nt = 0; nt < 2; ++nt)
            #pragma unroll
            for (int r = 0; r < 16; ++r)
                acc[mt][nt][r] = 0.f;

    #pragma unroll 4
    for (int ks = 0; ks < 32; ++ks) {
        const int slot = ks & 3;
        const int g8 = (((ks*2 + half) ^ ln31) << 3);
        bf16x8 a0 = *(const bf16x8*)&Albuf[ln31*512 + g8];
        bf16x8 a1 = *(const bf16x8*)&Albuf[16384 + ln31*512 + g8];
        __builtin_amdgcn_s_setprio(1);
        acc[0][0] = __builtin_amdgcn_mfma_f32_32x32x16_bf16(a0, bfr[slot][0], acc[0][0], 0, 0, 0);
        acc[1][0] = __builtin_amdgcn_mfma_f32_32x32x16_bf16(a1, bfr[slot][0], acc[1][0], 0, 0, 0);
        acc[0][1] = __builtin_amdgcn_mfma_f32_32x32x16_bf16(a0, bfr[slot][1], acc[0][1], 0, 0, 0);
        acc[1][1] = __builtin_amdgcn_mfma_f32_32x32x16_bf16(a1, bfr[slot][1], acc[1][1], 0, 0, 0);
        __builtin_amdgcn_s_setprio(0);
        // prefetch ks+4 (W2F padded by 4 ksteps -> branchless)
        bfr[slot][0] = Bp[((ks+4)*16 + wave*2 + 0)*64 + lane];
        bfr[slot][1] = Bp[((ks+4)*16 + wave*2 + 1)*64 + lane];
    }

    asm volatile("s_waitcnt lgkmcnt(0)" ::: "memory");
    __builtin_amdgcn_s_barrier();           // all waves done reading Albuf
    float* sred = (float*)Albuf;            // reuse LDS: [8 waves][64 rows]

    // --- epilogue: tanh + V-dot; mt-outer keeps register peak low ---
    #pragma unroll
    for (int mt = 0; mt < 2; ++mt) {
        float s[16];
        #pragma unroll
        for (int r = 0; r < 16; ++r) s[r] = 0.f;
        #pragma unroll
        for (int nt = 0; nt < 2; ++nt) {
            const float q = qv[nt], w = vw[nt];
            #pragma unroll
            for (int r = 0; r < 16; ++r) {
                float x = q + acc[mt][nt][r];
                float e = __expf(x + x);
                float rc = __builtin_amdgcn_rcpf(e + 1.f);
                s[r] = fmaf(fmaf(-2.f, rc, 1.f), w, s[r]);
            }
        }
        #pragma unroll
        for (int r = 0; r < 16; ++r) {
            float v = s[r];
            v += __shfl_xor(v, 1);
            v += __shfl_xor(v, 2);
            v += __shfl_xor(v, 4);
            v += __shfl_xor(v, 8);
            v += __shfl_xor(v, 16);
            if (ln31 == 0)
                sred[wave*64 + mt*32 + (r & 3) + 8*(r >> 2) + 4*half] = v;
        }
    }
    asm volatile("s_waitcnt lgkmcnt(0)" ::: "memory");
    __builtin_amdgcn_s_barrier();

    // --- redundant per-wave softmax: row = lane, p stays in registers ---
    float ssum = 0.f;
    #pragma unroll
    for (int w = 0; w < 8; ++w) ssum += sred[w*64 + lane];
    float mx = ssum;
    #pragma unroll
    for (int off = 32; off; off >>= 1) mx = fmaxf(mx, __shfl_xor(mx, off));
    float p = __expf(ssum - mx);
    float l = p;
    #pragma unroll
    for (int off = 32; off; off >>= 1) l += __shfl_xor(l, off);
    if (t == 0) { pm[blk] = mx; pl[blk] = l; }

    // --- context: each thread one d-column, p broadcast via shfl (L2-hot re-read) ---
    float ca = 0.f;
    const float* vcol = values + (size_t)m0*DD + t;
    #pragma unroll 8
    for (int r = 0; r < 64; ++r) {
        float pr = __shfl(p, r);
        ca = fmaf(pr, vcol[(size_t)r*DD], ca);
    }
    pv[(size_t)blk*DD + t] = ca;
}

// ---- finish: combine 32 chunks per batch with online-softmax rescale ----
__global__ void k_finish(const float* __restrict__ pv, const float* __restrict__ pm,
                         const float* __restrict__ pl, float* __restrict__ out) {
    __shared__ float sm_[32], sl_[32], sw[32];
    const int b = blockIdx.x, t = threadIdx.x;
    if (t < 32) { sm_[t] = pm[b*32 + t]; sl_[t] = pl[b*32 + t]; }
    __syncthreads();
    float M = -1e30f;
    #pragma unroll
    for (int c = 0; c < 32; ++c) M = fmaxf(M, sm_[c]);
    float L = 0.f;
    #pragma unroll
    for (int c = 0; c < 32; ++c) L += sl_[c] * __expf(sm_[c] - M);
    if (t < 32) sw[t] = __expf(sm_[t] - M) / L;
    __syncthreads();
    float2 a = make_float2(0.f, 0.f);
    #pragma unroll 4
    for (int c = 0; c < 32; ++c) {
        float w = sw[c];
        float2 v = *(const float2*)&pv[(size_t)(b*32 + c)*DD + t*2];
        a.x = fmaf(w, v.x, a.x);
        a.y = fmaf(w, v.y, a.y);
    }
    *(float2*)&out[(size_t)b*DD + t*2] = a;
}

extern "C" void kernel_launch(void* const* d_in, const int* in_sizes, int n_in,
                              void* d_out, int out_size, void* d_ws, size_t ws_size,
                              hipStream_t stream) {
    const float* query  = (const float*)d_in[0];
    const float* values = (const float*)d_in[1];
    const float* W1     = (const float*)d_in[2];
    const float* b1     = (const float*)d_in[3];
    const float* W2     = (const float*)d_in[4];
    const float* b2     = (const float*)d_in[5];
    const float* Vw     = (const float*)d_in[6];
    // d_in[7] = bv: softmax over s is shift-invariant -> no-op

    char* ws = (char*)d_ws;
    unsigned short* W2F = (unsigned short*)ws;            // 512 KB + 64 KB pad (depth-4 ring)
    float* qpb = (float*)(ws + 589824);                   // 128 KB
    float* pm  = (float*)(ws + 589824 + 131072);          // 8 KB
    float* pl  = (float*)(ws + 589824 + 131072 + 8192);   // 8 KB
    float* pv  = (float*)(ws + 589824 + 131072 + 16384);  // 4 MB

    k_prep<<<192, 256, 0, stream>>>(W2, W2F, query, W1, b1, b2, qpb);
    k_scores<<<BS/64, 512, 0, stream>>>(values, W2F, qpb, Vw, pm, pl, pv);
    k_finish<<<BB, 256, 0, stream>>>(pv, pm, pl, (float*)d_out);
}